// Round 5
// baseline (173.522 us; speedup 1.0000x reference)
//
#include <hip/hip_runtime.h>
#include <hip/hip_bf16.h>

// Two-pass radix-partition, round 5: full-occupancy partition pass.
//
// Algebra (unchanged): voxel = c>>1, u = c&1:
//   norm_center = mu = sum(u)/count, variance = mu*(1-mu),
//   density = count / glob[batch].  Per segment need only packed
//   (count, sum_ux, sum_uy, sum_uz) in one u32.
//
// r4 evidence: partition at 41 us, 16% occupancy, 2 TB/s — grid-starved
// (489 blocks, 1.9/CU). Fix: PTS=2048 -> 12.5 KB LDS -> 8 blocks/CU
// (32 waves/CU) and 1954 blocks. Payload writes stay dense at L2 since
// bucket cursors advance contiguously (r4: WRITE_SIZE ~= payload size).

#define BLOCK 256
#define PTS 2048             // points per pass-1 block
#define BUCKETS 256
#define SEG_SHIFT 12         // log2(SPB)
#define SPB 4096             // segments per bucket; S = BUCKETS*SPB = 2^20
#define BLOCK2 1024

__device__ __forceinline__ unsigned make_pay(int b, int x, int y, int z, int gs) {
    const int seg = (((b * gs + (x >> 1)) * gs + (y >> 1)) * gs) + (z >> 1);
    return ((unsigned)seg << 3) | ((unsigned)(x & 1) << 2)
         | ((unsigned)(y & 1) << 1) | (unsigned)(z & 1);
}

// ---------------- pass 1: partition points into bucket runs ----------------
__global__ __launch_bounds__(BLOCK)
void partition_kernel(const int* __restrict__ bidx,
                      const int* __restrict__ coords,
                      const int* __restrict__ gptr,
                      unsigned* __restrict__ payload,   // [BUCKETS * CAP]
                      unsigned* __restrict__ g_cursor,  // [BUCKETS]
                      int N, int CAP) {
    __shared__ unsigned s_pay[PTS];        // 8 KB sorted payloads
    __shared__ unsigned s_hist[BUCKETS];
    __shared__ unsigned s_base[BUCKETS];   // in-block exclusive offsets
    __shared__ unsigned s_old[BUCKETS];    // reserved global bases
    __shared__ unsigned s_cur[BUCKETS];

    const int tid = threadIdx.x;
    s_hist[tid] = 0u;
    s_cur[tid] = 0u;
    __syncthreads();

    const int gs = gptr[0] >> 1;           // output grid extent (64)
    const int base = blockIdx.x * PTS;
    const int cnt = min(PTS, N - base);

    const int4* __restrict__ bidx4 = (const int4*)bidx;
    const int4* __restrict__ crd4  = (const int4*)coords;

    // ---- phase A: bucket histogram (int4-coalesced, 4 points/thread/iter)
    #pragma unroll
    for (int g = 0; g < PTS / (BLOCK * 4); ++g) {
        const int p0 = base + (g * BLOCK + tid) * 4;
        if (p0 + 3 < N) {
            const int q = p0 >> 2;
            const int4 b4 = bidx4[q];
            const int4 c0 = crd4[3 * q + 0];
            const int4 c1 = crd4[3 * q + 1];
            const int4 c2 = crd4[3 * q + 2];
            atomicAdd(&s_hist[make_pay(b4.x, c0.x, c0.y, c0.z, gs) >> (SEG_SHIFT + 3)], 1u);
            atomicAdd(&s_hist[make_pay(b4.y, c0.w, c1.x, c1.y, gs) >> (SEG_SHIFT + 3)], 1u);
            atomicAdd(&s_hist[make_pay(b4.z, c1.z, c1.w, c2.x, gs) >> (SEG_SHIFT + 3)], 1u);
            atomicAdd(&s_hist[make_pay(b4.w, c2.y, c2.z, c2.w, gs) >> (SEG_SHIFT + 3)], 1u);
        } else {
            for (int p = p0; p < N && p < p0 + 4; ++p) {
                const unsigned pay = make_pay(bidx[p], coords[3 * p + 0],
                                              coords[3 * p + 1], coords[3 * p + 2], gs);
                atomicAdd(&s_hist[pay >> (SEG_SHIFT + 3)], 1u);
            }
        }
    }
    __syncthreads();

    // ---- phase B: exclusive scan (Hillis-Steele, BUCKETS==BLOCK) + reserve
    {
        const unsigned v = s_hist[tid];
        s_base[tid] = v;
        __syncthreads();
        for (int off = 1; off < BUCKETS; off <<= 1) {
            const unsigned t = (tid >= off) ? s_base[tid - off] : 0u;
            __syncthreads();
            s_base[tid] += t;
            __syncthreads();
        }
        const unsigned incl = s_base[tid];
        s_base[tid] = incl - v;                      // exclusive
        s_old[tid] = atomicAdd(&g_cursor[tid], v);   // 256 global atomics/block
        __syncthreads();
    }

    // ---- phase C: re-read (L2-warm), place payloads bucket-sorted in LDS
    #pragma unroll
    for (int g = 0; g < PTS / (BLOCK * 4); ++g) {
        const int p0 = base + (g * BLOCK + tid) * 4;
        if (p0 + 3 < N) {
            const int q = p0 >> 2;
            const int4 b4 = bidx4[q];
            const int4 c0 = crd4[3 * q + 0];
            const int4 c1 = crd4[3 * q + 1];
            const int4 c2 = crd4[3 * q + 2];
            unsigned pay, bk, r;
            pay = make_pay(b4.x, c0.x, c0.y, c0.z, gs); bk = pay >> (SEG_SHIFT + 3);
            r = atomicAdd(&s_cur[bk], 1u); s_pay[s_base[bk] + r] = pay;
            pay = make_pay(b4.y, c0.w, c1.x, c1.y, gs); bk = pay >> (SEG_SHIFT + 3);
            r = atomicAdd(&s_cur[bk], 1u); s_pay[s_base[bk] + r] = pay;
            pay = make_pay(b4.z, c1.z, c1.w, c2.x, gs); bk = pay >> (SEG_SHIFT + 3);
            r = atomicAdd(&s_cur[bk], 1u); s_pay[s_base[bk] + r] = pay;
            pay = make_pay(b4.w, c2.y, c2.z, c2.w, gs); bk = pay >> (SEG_SHIFT + 3);
            r = atomicAdd(&s_cur[bk], 1u); s_pay[s_base[bk] + r] = pay;
        } else {
            for (int p = p0; p < N && p < p0 + 4; ++p) {
                const unsigned pay = make_pay(bidx[p], coords[3 * p + 0],
                                              coords[3 * p + 1], coords[3 * p + 2], gs);
                const unsigned bk = pay >> (SEG_SHIFT + 3);
                const unsigned r = atomicAdd(&s_cur[bk], 1u);
                s_pay[s_base[bk] + r] = pay;
            }
        }
    }
    __syncthreads();

    // ---- phase D: coalesced copy-out (runs of ~8 per bucket)
    for (int j = tid; j < cnt; j += BLOCK) {
        const unsigned p = s_pay[j];
        const unsigned bk = p >> (SEG_SHIFT + 3);
        const unsigned off = s_old[bk] + ((unsigned)j - s_base[bk]);
        if (off < (unsigned)CAP)                     // >15-sigma safety guard
            payload[(size_t)bk * CAP + off] = p;
    }
}

// -------- pass 2: per-bucket LDS accumulation + fused finalize --------
__global__ __launch_bounds__(BLOCK2)
void stats_kernel(const unsigned* __restrict__ payload,
                  const unsigned* __restrict__ g_cursor,
                  float* __restrict__ out, int CAP) {
    __shared__ unsigned fine[SPB];   // 16 KB packed (count,ux,uy,uz)
    __shared__ unsigned s_g[64];

    const int tid = threadIdx.x;
    const int k = blockIdx.x;

    for (int s = tid; s < SPB; s += BLOCK2) fine[s] = 0u;
    if (tid < 64) s_g[tid] = g_cursor[(k & ~63) + tid];   // 64 buckets/batch
    __syncthreads();
    for (int o = 32; o > 0; o >>= 1) {
        if (tid < o) s_g[tid] += s_g[tid + o];
        __syncthreads();
    }
    const float ginv = 1.0f / (float)s_g[0];   // glob[batch]; unused if empty

    unsigned cnt = g_cursor[k];
    if (cnt > (unsigned)CAP) cnt = (unsigned)CAP;
    const uint4* __restrict__ pay4 = (const uint4*)(payload + (size_t)k * CAP);
    const unsigned n4 = cnt >> 2;

    for (unsigned j = tid; j < n4; j += BLOCK2) {
        const uint4 p = pay4[j];
        atomicAdd(&fine[(p.x >> 3) & (SPB - 1)],
                  (1u << 24) | ((p.x & 4u) << 14) | ((p.x & 2u) << 7) | (p.x & 1u));
        atomicAdd(&fine[(p.y >> 3) & (SPB - 1)],
                  (1u << 24) | ((p.y & 4u) << 14) | ((p.y & 2u) << 7) | (p.y & 1u));
        atomicAdd(&fine[(p.z >> 3) & (SPB - 1)],
                  (1u << 24) | ((p.z & 4u) << 14) | ((p.z & 2u) << 7) | (p.z & 1u));
        atomicAdd(&fine[(p.w >> 3) & (SPB - 1)],
                  (1u << 24) | ((p.w & 4u) << 14) | ((p.w & 2u) << 7) | (p.w & 1u));
    }
    for (unsigned j = (n4 << 2) + tid; j < cnt; j += BLOCK2) {
        const unsigned p = payload[(size_t)k * CAP + j];
        atomicAdd(&fine[(p >> 3) & (SPB - 1)],
                  (1u << 24) | ((p & 4u) << 14) | ((p & 2u) << 7) | (p & 1u));
    }
    __syncthreads();

    for (int s = tid; s < SPB; s += BLOCK2) {
        const unsigned a = fine[s];
        const int c = (int)(a >> 24);
        float d0 = 0.f, vx = 0.f, vy = 0.f, vz = 0.f, mx = 0.f, my = 0.f, mz = 0.f;
        if (c > 0) {
            const float inv = 1.0f / (float)c;
            mx = (float)((a >> 16) & 0xffu) * inv;
            my = (float)((a >> 8) & 0xffu) * inv;
            mz = (float)(a & 0xffu) * inv;
            vx = mx - mx * mx;
            vy = my - my * my;
            vz = mz - mz * mz;
            d0 = (float)c * ginv;
        }
        float* row = out + (size_t)(k * SPB + s) * 7;
        row[0] = d0;
        row[1] = vx; row[2] = vy; row[3] = vz;
        row[4] = mx; row[5] = my; row[6] = mz;
    }
}

// ---------------- fallback (round-2 path, known-good) ----------------
__global__ __launch_bounds__(BLOCK)
void accum_kernel(const int* __restrict__ bidx,
                  const int* __restrict__ coords,
                  const int* __restrict__ gptr,
                  unsigned* __restrict__ acc, int astride,
                  int* __restrict__ glob, int N) {
    __shared__ int gcnt[4];
    if (threadIdx.x < 4) gcnt[threadIdx.x] = 0;
    __syncthreads();
    const int gs = gptr[0] >> 1;
    int l0 = 0, l1 = 0, l2 = 0, l3 = 0;
    const int stride = gridDim.x * blockDim.x;
    for (int i = blockIdx.x * blockDim.x + threadIdx.x; i < N; i += stride) {
        const int b  = bidx[i];
        const int cx = coords[3 * i + 0];
        const int cy = coords[3 * i + 1];
        const int cz = coords[3 * i + 2];
        const int seg = (((b * gs + (cx >> 1)) * gs + (cy >> 1)) * gs) + (cz >> 1);
        const unsigned val = (1u << 24)
                           | ((unsigned)(cx & 1) << 16)
                           | ((unsigned)(cy & 1) << 8)
                           |  (unsigned)(cz & 1);
        atomicAdd(&acc[(size_t)seg * astride], val);
        l0 += (b == 0); l1 += (b == 1); l2 += (b == 2); l3 += (b == 3);
    }
    if (l0) atomicAdd(&gcnt[0], l0);
    if (l1) atomicAdd(&gcnt[1], l1);
    if (l2) atomicAdd(&gcnt[2], l2);
    if (l3) atomicAdd(&gcnt[3], l3);
    __syncthreads();
    if (threadIdx.x < 4 && gcnt[threadIdx.x] != 0)
        atomicAdd(&glob[threadIdx.x], gcnt[threadIdx.x]);
}

__global__ __launch_bounds__(BLOCK)
void finalize_kernel(const unsigned* __restrict__ acc, int astride,
                     const int* __restrict__ glob,
                     float* __restrict__ out, int S, int pbShift) {
    const int s = blockIdx.x * blockDim.x + threadIdx.x;
    if (s >= S) return;
    const unsigned a = acc[(size_t)s * astride];
    const int b = s >> pbShift;
    const int c = (int)(a >> 24);
    float d0 = 0.f, vx = 0.f, vy = 0.f, vz = 0.f, mx = 0.f, my = 0.f, mz = 0.f;
    if (c > 0) {
        const float inv = 1.0f / (float)c;
        mx = (float)((a >> 16) & 0xffu) * inv;
        my = (float)((a >> 8) & 0xffu) * inv;
        mz = (float)(a & 0xffu) * inv;
        vx = mx - mx * mx; vy = my - my * my; vz = mz - mz * mz;
        d0 = (float)c / (float)glob[b];
    }
    float* row = out + (size_t)s * 7;
    row[0] = d0;
    row[1] = vx; row[2] = vy; row[3] = vz;
    row[4] = mx; row[5] = my; row[6] = mz;
}

extern "C" void kernel_launch(void* const* d_in, const int* in_sizes, int n_in,
                              void* d_out, int out_size, void* d_ws, size_t ws_size,
                              hipStream_t stream) {
    const int* bidx   = (const int*)d_in[1];   // batch_idx [N]
    const int* coords = (const int*)d_in[2];   // coords [N,3]
    const int* gptr   = (const int*)d_in[3];   // grid_size scalar (128)

    const int N = in_sizes[1];
    const int S = out_size / 7;                // 1,048,576
    const int per_batch = S / 4;               // B = 4

    const int NpB = (N + BUCKETS - 1) / BUCKETS;
    const int CAP = ((NpB + NpB / 8 + 64) + 63) & ~63;   // ~+15 sigma headroom
    const size_t need = 1024 + (size_t)BUCKETS * (size_t)CAP * 4u;

    const bool fast = (S == (BUCKETS * SPB)) && (per_batch == (S / 4)) &&
                      (per_batch / SPB == 64) && (ws_size >= need) && (N > 0);

    if (fast) {
        unsigned* g_cursor = (unsigned*)d_ws;                 // 1 KB
        unsigned* payload  = (unsigned*)((char*)d_ws + 1024); // 256*CAP u32
        hipMemsetAsync(d_ws, 0, 1024, stream);

        const int blocks = (N + PTS - 1) / PTS;               // 1954
        partition_kernel<<<blocks, BLOCK, 0, stream>>>(
            bidx, coords, gptr, payload, g_cursor, N, CAP);
        stats_kernel<<<BUCKETS, BLOCK2, 0, stream>>>(
            payload, g_cursor, (float*)d_out, CAP);
    } else {
        // known-good round-2 path
        int pbShift = 0;
        while ((1 << pbShift) < per_batch) ++pbShift;
        int* glob = (int*)d_ws;
        const size_t accBytes = (size_t)S * sizeof(unsigned);
        unsigned* acc;
        int astride;
        if (ws_size >= accBytes + 64) {
            acc = (unsigned*)((char*)d_ws + 64);
            astride = 1;
            hipMemsetAsync(d_ws, 0, 64 + accBytes, stream);
        } else {
            acc = (unsigned*)d_out;
            astride = 7;
            hipMemsetAsync(d_out, 0, (size_t)out_size * sizeof(float), stream);
            hipMemsetAsync(d_ws, 0, 64, stream);
        }
        int accBlocks = (N + BLOCK - 1) / BLOCK;
        if (accBlocks > 2048) accBlocks = 2048;
        accum_kernel<<<accBlocks, BLOCK, 0, stream>>>(bidx, coords, gptr,
                                                      acc, astride, glob, N);
        const int finBlocks = (S + BLOCK - 1) / BLOCK;
        finalize_kernel<<<finBlocks, BLOCK, 0, stream>>>(acc, astride, glob,
                                                         (float*)d_out, S, pbShift);
    }
}

// Round 6
// 148.583 us; speedup vs baseline: 1.1679x; 1.1679x over previous
//
#include <hip/hip_runtime.h>
#include <hip/hip_bf16.h>

// Two-pass radix-partition, round 6.
//
// Algebra (unchanged): voxel = c>>1, u = c&1:
//   norm_center = mu = sum(u)/count, variance = mu*(1-mu),
//   density = count / glob[batch].  Per segment need only packed
//   (count, sum_ux, sum_uy, sum_uz) in one u32.
//
// r4 vs r5 evidence: PTS=8192 geometry is right (dense 128B runs, few
// cursor atomics, WRITE 18 MB); r5's PTS=2048 regressed via write
// amplification (30 MB) + per-block overhead. r4's real problem was
// latency: ~5 waves/CU hiding a per-thread dependent LDS-atomic chain.
// Fix: same PTS, 1024 threads/block -> ~30 waves/CU. Stats: stage rows
// in LDS, write coalesced float4 (was stride-28B scalar).

#define BLOCK1 1024          // partition threads/block
#define PTS 8192             // points per pass-1 block (geometry as r4)
#define BUCKETS 256
#define SEG_SHIFT 12         // log2(SPB)
#define SPB 4096             // segments per bucket; S = BUCKETS*SPB = 2^20
#define BLOCK2 1024
#define FBLOCK 256           // fallback path block size

__device__ __forceinline__ unsigned make_pay(int b, int x, int y, int z, int gs) {
    const int seg = (((b * gs + (x >> 1)) * gs + (y >> 1)) * gs) + (z >> 1);
    return ((unsigned)seg << 3) | ((unsigned)(x & 1) << 2)
         | ((unsigned)(y & 1) << 1) | (unsigned)(z & 1);
}

// ---------------- pass 1: partition points into bucket runs ----------------
__global__ __launch_bounds__(BLOCK1, 8)
void partition_kernel(const int* __restrict__ bidx,
                      const int* __restrict__ coords,
                      const int* __restrict__ gptr,
                      unsigned* __restrict__ payload,   // [BUCKETS * CAP]
                      unsigned* __restrict__ g_cursor,  // [BUCKETS]
                      int N, int CAP) {
    __shared__ unsigned s_pay[PTS];        // 32 KB sorted payloads
    __shared__ unsigned s_hist[BUCKETS];
    __shared__ unsigned s_base[BUCKETS];   // in-block exclusive offsets
    __shared__ unsigned s_old[BUCKETS];    // reserved global bases
    __shared__ unsigned s_cur[BUCKETS];

    const int tid = threadIdx.x;
    if (tid < BUCKETS) { s_hist[tid] = 0u; s_cur[tid] = 0u; }
    __syncthreads();

    const int gs = gptr[0] >> 1;           // output grid extent (64)
    const int base = blockIdx.x * PTS;
    const int cnt = min(PTS, N - base);

    const int4* __restrict__ bidx4 = (const int4*)bidx;
    const int4* __restrict__ crd4  = (const int4*)coords;

    // ---- phase A: bucket histogram (int4, 4 points/thread/iter, 2 iters)
    #pragma unroll
    for (int g = 0; g < PTS / (BLOCK1 * 4); ++g) {
        const int p0 = base + (g * BLOCK1 + tid) * 4;
        if (p0 + 3 < N) {
            const int q = p0 >> 2;
            const int4 b4 = bidx4[q];
            const int4 c0 = crd4[3 * q + 0];
            const int4 c1 = crd4[3 * q + 1];
            const int4 c2 = crd4[3 * q + 2];
            atomicAdd(&s_hist[make_pay(b4.x, c0.x, c0.y, c0.z, gs) >> (SEG_SHIFT + 3)], 1u);
            atomicAdd(&s_hist[make_pay(b4.y, c0.w, c1.x, c1.y, gs) >> (SEG_SHIFT + 3)], 1u);
            atomicAdd(&s_hist[make_pay(b4.z, c1.z, c1.w, c2.x, gs) >> (SEG_SHIFT + 3)], 1u);
            atomicAdd(&s_hist[make_pay(b4.w, c2.y, c2.z, c2.w, gs) >> (SEG_SHIFT + 3)], 1u);
        } else {
            for (int p = p0; p < N && p < p0 + 4; ++p) {
                const unsigned pay = make_pay(bidx[p], coords[3 * p + 0],
                                              coords[3 * p + 1], coords[3 * p + 2], gs);
                atomicAdd(&s_hist[pay >> (SEG_SHIFT + 3)], 1u);
            }
        }
    }
    __syncthreads();

    // ---- phase B: exclusive scan over 256 buckets (tid<256 active) + reserve
    {
        unsigned v = 0u;
        if (tid < BUCKETS) { v = s_hist[tid]; s_base[tid] = v; }
        __syncthreads();
        for (int off = 1; off < BUCKETS; off <<= 1) {
            unsigned t = 0u;
            if (tid < BUCKETS && tid >= off) t = s_base[tid - off];
            __syncthreads();
            if (tid < BUCKETS) s_base[tid] += t;
            __syncthreads();
        }
        if (tid < BUCKETS) {
            s_base[tid] -= v;                            // exclusive
            s_old[tid] = atomicAdd(&g_cursor[tid], v);   // 256 atomics/block
        }
        __syncthreads();
    }

    // ---- phase C: re-read (L2-warm), place payloads bucket-sorted in LDS
    #pragma unroll
    for (int g = 0; g < PTS / (BLOCK1 * 4); ++g) {
        const int p0 = base + (g * BLOCK1 + tid) * 4;
        if (p0 + 3 < N) {
            const int q = p0 >> 2;
            const int4 b4 = bidx4[q];
            const int4 c0 = crd4[3 * q + 0];
            const int4 c1 = crd4[3 * q + 1];
            const int4 c2 = crd4[3 * q + 2];
            unsigned pay, bk, r;
            pay = make_pay(b4.x, c0.x, c0.y, c0.z, gs); bk = pay >> (SEG_SHIFT + 3);
            r = atomicAdd(&s_cur[bk], 1u); s_pay[s_base[bk] + r] = pay;
            pay = make_pay(b4.y, c0.w, c1.x, c1.y, gs); bk = pay >> (SEG_SHIFT + 3);
            r = atomicAdd(&s_cur[bk], 1u); s_pay[s_base[bk] + r] = pay;
            pay = make_pay(b4.z, c1.z, c1.w, c2.x, gs); bk = pay >> (SEG_SHIFT + 3);
            r = atomicAdd(&s_cur[bk], 1u); s_pay[s_base[bk] + r] = pay;
            pay = make_pay(b4.w, c2.y, c2.z, c2.w, gs); bk = pay >> (SEG_SHIFT + 3);
            r = atomicAdd(&s_cur[bk], 1u); s_pay[s_base[bk] + r] = pay;
        } else {
            for (int p = p0; p < N && p < p0 + 4; ++p) {
                const unsigned pay = make_pay(bidx[p], coords[3 * p + 0],
                                              coords[3 * p + 1], coords[3 * p + 2], gs);
                const unsigned bk = pay >> (SEG_SHIFT + 3);
                const unsigned r = atomicAdd(&s_cur[bk], 1u);
                s_pay[s_base[bk] + r] = pay;
            }
        }
    }
    __syncthreads();

    // ---- phase D: coalesced copy-out (runs of ~32 per bucket)
    for (int j = tid; j < cnt; j += BLOCK1) {
        const unsigned p = s_pay[j];
        const unsigned bk = p >> (SEG_SHIFT + 3);
        const unsigned off = s_old[bk] + ((unsigned)j - s_base[bk]);
        if (off < (unsigned)CAP)                     // >15-sigma safety guard
            payload[(size_t)bk * CAP + off] = p;
    }
}

// -------- pass 2: per-bucket LDS accumulation + fused finalize --------
__global__ __launch_bounds__(BLOCK2)
void stats_kernel(const unsigned* __restrict__ payload,
                  const unsigned* __restrict__ g_cursor,
                  float* __restrict__ out, int CAP) {
    __shared__ unsigned fine[SPB];        // 16 KB packed (count,ux,uy,uz)
    __shared__ float s_stage[BLOCK2 * 7]; // 28 KB row staging for coalesced out
    __shared__ unsigned s_g[64];

    const int tid = threadIdx.x;
    const int k = blockIdx.x;

    for (int s = tid; s < SPB; s += BLOCK2) fine[s] = 0u;
    if (tid < 64) s_g[tid] = g_cursor[(k & ~63) + tid];   // 64 buckets/batch
    __syncthreads();
    for (int o = 32; o > 0; o >>= 1) {
        if (tid < o) s_g[tid] += s_g[tid + o];
        __syncthreads();
    }
    const float ginv = 1.0f / (float)s_g[0];   // glob[batch]; unused if empty

    unsigned cnt = g_cursor[k];
    if (cnt > (unsigned)CAP) cnt = (unsigned)CAP;
    const uint4* __restrict__ pay4 = (const uint4*)(payload + (size_t)k * CAP);
    const unsigned n4 = cnt >> 2;

    for (unsigned j = tid; j < n4; j += BLOCK2) {
        const uint4 p = pay4[j];
        atomicAdd(&fine[(p.x >> 3) & (SPB - 1)],
                  (1u << 24) | ((p.x & 4u) << 14) | ((p.x & 2u) << 7) | (p.x & 1u));
        atomicAdd(&fine[(p.y >> 3) & (SPB - 1)],
                  (1u << 24) | ((p.y & 4u) << 14) | ((p.y & 2u) << 7) | (p.y & 1u));
        atomicAdd(&fine[(p.z >> 3) & (SPB - 1)],
                  (1u << 24) | ((p.z & 4u) << 14) | ((p.z & 2u) << 7) | (p.z & 1u));
        atomicAdd(&fine[(p.w >> 3) & (SPB - 1)],
                  (1u << 24) | ((p.w & 4u) << 14) | ((p.w & 2u) << 7) | (p.w & 1u));
    }
    for (unsigned j = (n4 << 2) + tid; j < cnt; j += BLOCK2) {
        const unsigned p = payload[(size_t)k * CAP + j];
        atomicAdd(&fine[(p >> 3) & (SPB - 1)],
                  (1u << 24) | ((p & 4u) << 14) | ((p & 2u) << 7) | (p & 1u));
    }
    __syncthreads();

    // finalize in 4 tiles of 1024 rows: compute -> LDS stage -> float4 out
    for (int t = 0; t < SPB; t += BLOCK2) {
        const unsigned a = fine[t + tid];
        const int c = (int)(a >> 24);
        float d0 = 0.f, vx = 0.f, vy = 0.f, vz = 0.f, mx = 0.f, my = 0.f, mz = 0.f;
        if (c > 0) {
            const float inv = 1.0f / (float)c;
            mx = (float)((a >> 16) & 0xffu) * inv;
            my = (float)((a >> 8) & 0xffu) * inv;
            mz = (float)(a & 0xffu) * inv;
            vx = mx - mx * mx;
            vy = my - my * my;
            vz = mz - mz * mz;
            d0 = (float)c * ginv;
        }
        float* st = &s_stage[tid * 7];
        st[0] = d0;
        st[1] = vx; st[2] = vy; st[3] = vz;
        st[4] = mx; st[5] = my; st[6] = mz;
        __syncthreads();

        const float4* src = (const float4*)s_stage;
        float4* dst = (float4*)(out + ((size_t)k * SPB + t) * 7);
        #pragma unroll
        for (int j = 0; j < (BLOCK2 * 7) / (4 * BLOCK2) + 1; ++j) {
            const int idx = j * BLOCK2 + tid;
            if (idx < (BLOCK2 * 7) / 4) dst[idx] = src[idx];
        }
        __syncthreads();
    }
}

// ---------------- fallback (round-2 path, known-good) ----------------
__global__ __launch_bounds__(FBLOCK)
void accum_kernel(const int* __restrict__ bidx,
                  const int* __restrict__ coords,
                  const int* __restrict__ gptr,
                  unsigned* __restrict__ acc, int astride,
                  int* __restrict__ glob, int N) {
    __shared__ int gcnt[4];
    if (threadIdx.x < 4) gcnt[threadIdx.x] = 0;
    __syncthreads();
    const int gs = gptr[0] >> 1;
    int l0 = 0, l1 = 0, l2 = 0, l3 = 0;
    const int stride = gridDim.x * blockDim.x;
    for (int i = blockIdx.x * blockDim.x + threadIdx.x; i < N; i += stride) {
        const int b  = bidx[i];
        const int cx = coords[3 * i + 0];
        const int cy = coords[3 * i + 1];
        const int cz = coords[3 * i + 2];
        const int seg = (((b * gs + (cx >> 1)) * gs + (cy >> 1)) * gs) + (cz >> 1);
        const unsigned val = (1u << 24)
                           | ((unsigned)(cx & 1) << 16)
                           | ((unsigned)(cy & 1) << 8)
                           |  (unsigned)(cz & 1);
        atomicAdd(&acc[(size_t)seg * astride], val);
        l0 += (b == 0); l1 += (b == 1); l2 += (b == 2); l3 += (b == 3);
    }
    if (l0) atomicAdd(&gcnt[0], l0);
    if (l1) atomicAdd(&gcnt[1], l1);
    if (l2) atomicAdd(&gcnt[2], l2);
    if (l3) atomicAdd(&gcnt[3], l3);
    __syncthreads();
    if (threadIdx.x < 4 && gcnt[threadIdx.x] != 0)
        atomicAdd(&glob[threadIdx.x], gcnt[threadIdx.x]);
}

__global__ __launch_bounds__(FBLOCK)
void finalize_kernel(const unsigned* __restrict__ acc, int astride,
                     const int* __restrict__ glob,
                     float* __restrict__ out, int S, int pbShift) {
    const int s = blockIdx.x * blockDim.x + threadIdx.x;
    if (s >= S) return;
    const unsigned a = acc[(size_t)s * astride];
    const int b = s >> pbShift;
    const int c = (int)(a >> 24);
    float d0 = 0.f, vx = 0.f, vy = 0.f, vz = 0.f, mx = 0.f, my = 0.f, mz = 0.f;
    if (c > 0) {
        const float inv = 1.0f / (float)c;
        mx = (float)((a >> 16) & 0xffu) * inv;
        my = (float)((a >> 8) & 0xffu) * inv;
        mz = (float)(a & 0xffu) * inv;
        vx = mx - mx * mx; vy = my - my * my; vz = mz - mz * mz;
        d0 = (float)c / (float)glob[b];
    }
    float* row = out + (size_t)s * 7;
    row[0] = d0;
    row[1] = vx; row[2] = vy; row[3] = vz;
    row[4] = mx; row[5] = my; row[6] = mz;
}

extern "C" void kernel_launch(void* const* d_in, const int* in_sizes, int n_in,
                              void* d_out, int out_size, void* d_ws, size_t ws_size,
                              hipStream_t stream) {
    const int* bidx   = (const int*)d_in[1];   // batch_idx [N]
    const int* coords = (const int*)d_in[2];   // coords [N,3]
    const int* gptr   = (const int*)d_in[3];   // grid_size scalar (128)

    const int N = in_sizes[1];
    const int S = out_size / 7;                // 1,048,576
    const int per_batch = S / 4;               // B = 4

    const int NpB = (N + BUCKETS - 1) / BUCKETS;
    const int CAP = ((NpB + NpB / 8 + 64) + 63) & ~63;   // ~+15 sigma headroom
    const size_t need = 1024 + (size_t)BUCKETS * (size_t)CAP * 4u;

    const bool fast = (S == (BUCKETS * SPB)) && (per_batch == (S / 4)) &&
                      (per_batch / SPB == 64) && (ws_size >= need) && (N > 0);

    if (fast) {
        unsigned* g_cursor = (unsigned*)d_ws;                 // 1 KB
        unsigned* payload  = (unsigned*)((char*)d_ws + 1024); // 256*CAP u32
        hipMemsetAsync(d_ws, 0, 1024, stream);

        const int blocks = (N + PTS - 1) / PTS;               // 489
        partition_kernel<<<blocks, BLOCK1, 0, stream>>>(
            bidx, coords, gptr, payload, g_cursor, N, CAP);
        stats_kernel<<<BUCKETS, BLOCK2, 0, stream>>>(
            payload, g_cursor, (float*)d_out, CAP);
    } else {
        // known-good round-2 path
        int pbShift = 0;
        while ((1 << pbShift) < per_batch) ++pbShift;
        int* glob = (int*)d_ws;
        const size_t accBytes = (size_t)S * sizeof(unsigned);
        unsigned* acc;
        int astride;
        if (ws_size >= accBytes + 64) {
            acc = (unsigned*)((char*)d_ws + 64);
            astride = 1;
            hipMemsetAsync(d_ws, 0, 64 + accBytes, stream);
        } else {
            acc = (unsigned*)d_out;
            astride = 7;
            hipMemsetAsync(d_out, 0, (size_t)out_size * sizeof(float), stream);
            hipMemsetAsync(d_ws, 0, 64, stream);
        }
        int accBlocks = (N + FBLOCK - 1) / FBLOCK;
        if (accBlocks > 2048) accBlocks = 2048;
        accum_kernel<<<accBlocks, FBLOCK, 0, stream>>>(bidx, coords, gptr,
                                                       acc, astride, glob, N);
        const int finBlocks = (S + FBLOCK - 1) / FBLOCK;
        finalize_kernel<<<finBlocks, FBLOCK, 0, stream>>>(acc, astride, glob,
                                                          (float*)d_out, S, pbShift);
    }
}